// Round 3
// baseline (409.413 us; speedup 1.0000x reference)
//
#include <hip/hip_runtime.h>
#include <hip/hip_bf16.h>
#include <stdint.h>

typedef unsigned short u16;
typedef unsigned int u32;
typedef unsigned long long u64;
typedef __bf16 bf16x8 __attribute__((ext_vector_type(8)));
typedef _Float16 f16x8 __attribute__((ext_vector_type(8)));
typedef float f32x4 __attribute__((ext_vector_type(4)));

#define M_ROWS 32768   // bs*seq
#define DIM    1024    // inp_dim
#define NPROJ  64
#define NBINS  20
#define FDIM   1280    // NPROJ*NBINS
#define EDIM   1024    // emb_dim

// round-to-nearest-even f32 -> bf16 (no NaNs in this problem)
__device__ __forceinline__ u16 f2bf(float f) {
    union { float f; u32 u; } v; v.f = f;
    return (u16)((v.u + 0x7FFFu + ((v.u >> 16) & 1u)) >> 16);
}

__device__ __forceinline__ float wave_sum(float v) {
    #pragma unroll
    for (int o = 32; o > 0; o >>= 1) v += __shfl_down(v, o, 64);
    return v;
}

__device__ __forceinline__ void gl_lds16(const void* g, void* l) {
    __builtin_amdgcn_global_load_lds(
        (const __attribute__((address_space(1))) void*)g,
        (__attribute__((address_space(3))) void*)l, 16, 0, 0);
}

__device__ __forceinline__ f32x4 mfma16(f16x8 a, f16x8 b, f32x4 c) {
    return __builtin_amdgcn_mfma_f32_16x16x32_f16(a, b, c, 0, 0, 0);
}

// scaled f16 split: f = hi + lo*2^-12, lo kept in normal f16 range.
__device__ __forceinline__ void split8(const float* f, f16x8& hi, f16x8& lo) {
    #pragma unroll
    for (int e = 0; e < 8; e++) {
        _Float16 h = (_Float16)f[e];
        hi[e] = h;
        lo[e] = (_Float16)((f[e] - (float)h) * 4096.0f);
    }
}

// ---------------------------------------------------------------------------
// K1: normalize proj_weight rows, split to f16 hi / scaled-lo, and store as
// PRE-SWIZZLED per-K-step tile images so k_fused can global_load_lds them
// linearly and read fragments with the XOR swizzle (G21: both-sides).
// Image: 16 steps x [64 proj][64 k] f16, byte-in-tile = p*128 + (k2 ^ ((p&7)<<4)).
// 64 blocks x 256 threads (one block per proj row, thread t -> k=4t..4t+3).
__global__ void k_norm_w(const float* __restrict__ w, u16* __restrict__ wswh,
                         u16* __restrict__ wswl) {
    int j = blockIdx.x;
    int t = threadIdx.x;
    float4 v = ((const float4*)(w + (size_t)j * DIM))[t];
    float ss = v.x*v.x + v.y*v.y + v.z*v.z + v.w*v.w;
    ss = wave_sum(ss);
    __shared__ float red[4];
    if ((t & 63) == 0) red[t >> 6] = ss;
    __syncthreads();
    float rn = 1.0f / fmaxf(sqrtf(red[0] + red[1] + red[2] + red[3]), 1e-12f);
    float wn[4] = {v.x*rn, v.y*rn, v.z*rn, v.w*rn};
    u64 hp = 0, lp = 0;
    #pragma unroll
    for (int e = 0; e < 4; e++) {
        _Float16 h = (_Float16)wn[e];
        _Float16 l = (_Float16)((wn[e] - (float)h) * 4096.0f);
        union { _Float16 f; u16 u; } ch, cl;
        ch.f = h; cl.f = l;
        hp |= (u64)ch.u << (16 * e);
        lp |= (u64)cl.u << (16 * e);
    }
    int s   = t >> 4;            // K-step (64 fp32 k per step)
    int kk2 = (t & 15) * 8;      // byte col within tile row (k*2)
    int off = s * 8192 + j * 128 + (kk2 ^ ((j & 7) << 4));  // 8B write stays in 16B swz unit
    *(u64*)((char*)wswh + off) = hp;
    *(u64*)((char*)wswl + off) = lp;
}

// ---------------------------------------------------------------------------
// K3: emb_weight fp32 -> bf16, same [EDIM][FDIM] layout. 1280 blocks.
__global__ void k_cvt(const float* __restrict__ s, u16* __restrict__ d) {
    int i = blockIdx.x * 256 + threadIdx.x;
    float4 v = ((const float4*)s)[i];
    ushort4 o; o.x = f2bf(v.x); o.y = f2bf(v.y); o.z = f2bf(v.z); o.w = f2bf(v.w);
    ((ushort4*)d)[i] = o;
}

// ---------------------------------------------------------------------------
// K_FUSED v2 (unchanged this round): rnx + GEMM1(MFMA f16-split) + act.
__global__ __launch_bounds__(256) void k_fused(const float* __restrict__ x,
        const u16* __restrict__ wswh, const u16* __restrict__ wswl,
        const float* __restrict__ mean, u16* __restrict__ z) {
    __shared__ u16 Bh[2][4096];      // 8KB/buf: [64 proj][64 k] f16, row-swizzled
    __shared__ u16 Bl[2][4096];
    __shared__ float pl[64 * 68];    // stride 68: 2-way (free) banks both phases
    __shared__ float mlds[64 * 21];  // mean, stride 21 (2-way banks in act)
    __shared__ float rnl[64];

    int t = threadIdx.x;
    int lane = t & 63, wave = t >> 6;
    int m16 = lane & 15, q = lane >> 4;
    int bm = blockIdx.x * 64;
    int wm = wave * 16;
    const float* xr = x + (size_t)(bm + wm + m16) * DIM;   // this lane's A row

    // stage means (read in act phase only; any later barrier covers)
    for (int i = t; i < 64 * 21; i += 256) {
        int j = i / 21, b = i - j * 21;
        if (b < 20) mlds[i] = mean[j * 20 + b];
    }

    f32x4 accA[4], accB[4];
    #pragma unroll
    for (int j = 0; j < 4; j++) { accA[j] = (f32x4){0,0,0,0}; accB[j] = (f32x4){0,0,0,0}; }
    float ssl = 0.f;

    // prologue: stage B(0), load A(0)
    gl_lds16(wswh + (size_t)t * 8,        &Bh[0][t * 8]);
    gl_lds16(wswh + 2048 + (size_t)t * 8, &Bh[0][2048 + t * 8]);
    gl_lds16(wswl + (size_t)t * 8,        &Bl[0][t * 8]);
    gl_lds16(wswl + 2048 + (size_t)t * 8, &Bl[0][2048 + t * 8]);
    float4 c0 = *(const float4*)(xr + q * 8);
    float4 c1 = *(const float4*)(xr + q * 8 + 4);
    float4 c2 = *(const float4*)(xr + q * 8 + 32);
    float4 c3 = *(const float4*)(xr + q * 8 + 36);

    for (int s = 0; s < 16; s++) {
        __syncthreads();   // B(s) staged, A(s) regs arrived (vmcnt drain)

        float4 n0, n1, n2, n3;
        if (s < 15) {
            const u16* sh = wswh + (size_t)(s + 1) * 4096;
            const u16* sl = wswl + (size_t)(s + 1) * 4096;
            u16* dh = &Bh[(s + 1) & 1][0];
            u16* dl = &Bl[(s + 1) & 1][0];
            gl_lds16(sh + t * 8,        dh + t * 8);
            gl_lds16(sh + 2048 + t * 8, dh + 2048 + t * 8);
            gl_lds16(sl + t * 8,        dl + t * 8);
            gl_lds16(sl + 2048 + t * 8, dl + 2048 + t * 8);
            const float* xn = xr + (s + 1) * 64 + q * 8;
            n0 = *(const float4*)(xn);
            n1 = *(const float4*)(xn + 4);
            n2 = *(const float4*)(xn + 32);
            n3 = *(const float4*)(xn + 36);
        }

        ssl += c0.x*c0.x + c0.y*c0.y + c0.z*c0.z + c0.w*c0.w;
        ssl += c1.x*c1.x + c1.y*c1.y + c1.z*c1.z + c1.w*c1.w;
        ssl += c2.x*c2.x + c2.y*c2.y + c2.z*c2.z + c2.w*c2.w;
        ssl += c3.x*c3.x + c3.y*c3.y + c3.z*c3.z + c3.w*c3.w;

        float av0[8] = {c0.x, c0.y, c0.z, c0.w, c1.x, c1.y, c1.z, c1.w};
        float av1[8] = {c2.x, c2.y, c2.z, c2.w, c3.x, c3.y, c3.z, c3.w};
        f16x8 ah[2], al[2];
        split8(av0, ah[0], al[0]);
        split8(av1, ah[1], al[1]);

        const char* bhp = (const char*)&Bh[s & 1][0];
        const char* blp = (const char*)&Bl[s & 1][0];
        #pragma unroll
        for (int ks = 0; ks < 2; ks++) {
            #pragma unroll
            for (int j = 0; j < 4; j++) {
                int P = j * 16 + m16;
                int off = P * 128 + ((q * 16 + ks * 64) ^ ((m16 & 7) << 4));
                f16x8 bh = *(const f16x8*)(bhp + off);
                f16x8 bl = *(const f16x8*)(blp + off);
                accA[j] = mfma16(ah[ks], bh, accA[j]);
                accB[j] = mfma16(ah[ks], bl, accB[j]);
                accB[j] = mfma16(al[ks], bh, accB[j]);
            }
        }
        c0 = n0; c1 = n1; c2 = n2; c3 = n3;
    }

    // --- rnx: 4 q-lanes of a row hold disjoint partials
    ssl += __shfl_xor(ssl, 16, 64);
    ssl += __shfl_xor(ssl, 32, 64);
    if (q == 0) rnl[wm + m16] = 1.0f / fmaxf(sqrtf(ssl), 1e-12f);
    __syncthreads();

    // --- p = (accA + accB*2^-12) * rnx -> pl   (C layout: row q*4+r, col m16)
    #pragma unroll
    for (int r = 0; r < 4; r++) {
        int row = wm + q * 4 + r;
        float rr = rnl[row];
        #pragma unroll
        for (int j = 0; j < 4; j++)
            pl[row * 68 + j * 16 + m16] =
                (accA[j][r] + accB[j][r] * 2.44140625e-4f) * rr;
    }
    __syncthreads();

    // --- act: thread owns projs 4c..4c+3 of rows rt+16*it -> 160B z chunks
    int c = t & 15;
    int rt = t >> 4;
    #pragma unroll 1
    for (int it = 0; it < 4; it++) {
        int row = rt + 16 * it;
        const float* prow = &pl[row * 68 + c * 4];
        float pp[4] = {prow[0], prow[1], prow[2], prow[3]};
        u32 packed[40];
        #pragma unroll
        for (int jj = 0; jj < 4; jj++) {
            float pv = pp[jj];
            const float* mj = &mlds[(c * 4 + jj) * 21];
            float act[NBINS];
            float top0 = -1e30f, top1 = -1e30f, top2 = -1e30f, top3 = -1e30f;
            #pragma unroll
            for (int b = 0; b < NBINS; b++) {
                float d = pv - mj[b];
                float a = __expf(-50.0f * d * d);   // 0.5/sigma2 = 50
                act[b] = a;
                if (a > top3) {
                    if (a > top0)      { top3 = top2; top2 = top1; top1 = top0; top0 = a; }
                    else if (a > top1) { top3 = top2; top2 = top1; top1 = a; }
                    else if (a > top2) { top3 = top2; top2 = a; }
                    else               { top3 = a; }
                }
            }
            float ss = 0.f;
            #pragma unroll
            for (int b = 0; b < NBINS; b++) {
                float a = (act[b] >= top3) ? act[b] : 0.0f;   // keep ties
                act[b] = a;
                ss += a * a;
            }
            float rr = 1.0f / fmaxf(sqrtf(ss), 1e-12f);
            #pragma unroll
            for (int i2 = 0; i2 < 10; i2++) {
                u32 lo = f2bf(act[2 * i2] * rr);
                u32 hi = f2bf(act[2 * i2 + 1] * rr);
                packed[jj * 10 + i2] = lo | (hi << 16);
            }
        }
        uint4* zp = (uint4*)(z + ((size_t)(bm + row) * FDIM + c * 80));
        #pragma unroll
        for (int u2 = 0; u2 < 10; u2++)
            zp[u2] = make_uint4(packed[4*u2], packed[4*u2+1], packed[4*u2+2], packed[4*u2+3]);
    }
}

// ---------------------------------------------------------------------------
// K6 v2: GEMM2 bf16 MFMA, depth-3 software pipeline (T3+T4).
// 4 LDS tile-buffers, raw s_barrier, counted vmcnt(8) -> loads span 3 steps,
// no full drain in the main loop. Race-free: stage(t+3) writes buf[(t-1)&3],
// whose last readers finished before this step's barrier (MFMA data-deps
// force lgkmcnt before a wave reaches it); steps t..t+2 read other buffers.
// vmcnt retires in issue order [m135], so vmcnt(8) with <=12 outstanding
// guarantees tile t's 4 loads landed. Tail peeled: vmcnt(8)/(4)/(0).
__global__ __launch_bounds__(256) void k_gemm2(const u16* __restrict__ A,
                                               const u16* __restrict__ B,
                                               float* __restrict__ C) {
    const int K = FDIM, N = EDIM;
    __shared__ u16 As[4][128 * 32];   // 4 x 8KB
    __shared__ u16 Bs[4][128 * 32];   // 4 x 8KB  (total 64KB -> 2 blocks/CU)
    int t = threadIdx.x;
    int lane = t & 63, wave = t >> 6;
    int sfl  = (blockIdx.y << 3) | blockIdx.x;        // hw dispatch order (x fastest)
    int tile = ((sfl & 7) << 8) | (sfl >> 3);         // xcd*256 + idx-in-xcd
    int bm = (tile >> 3) * 128;                       // 0..255 M-tiles
    int bn = (tile & 7) * 128;                        // 0..7   N-tiles
    int wm = (wave >> 1) * 64, wn = (wave & 1) * 64;
    int m16 = lane & 15, q = lane >> 4;

    f32x4 zero = {0.f, 0.f, 0.f, 0.f};
    f32x4 acc[4][4];
    #pragma unroll
    for (int i = 0; i < 4; i++)
        #pragma unroll
        for (int j = 0; j < 4; j++) acc[i][j] = zero;

    // staging map: thread t -> row sr (0..63, and +64), 8-elem chunk sc.
    int sr = t >> 2;
    int sc = (t & 3) * 8;
    const u16* ga = A + (size_t)(bm + sr) * K + sc;
    const u16* gb = B + (size_t)(bn + sr) * K + sc;

    auto stage = [&](int tt) {
        int b = tt & 3;
        const u16* gA = ga + tt * 32;
        const u16* gB = gb + tt * 32;
        u16* lA = &As[b][sr * 32 + sc];
        u16* lB = &Bs[b][sr * 32 + sc];
        gl_lds16(gA,                  lA);
        gl_lds16(gA + (size_t)64 * K, lA + 64 * 32);
        gl_lds16(gB,                  lB);
        gl_lds16(gB + (size_t)64 * K, lB + 64 * 32);
    };
    auto compute = [&](int tt) {
        int b = tt & 3;
        bf16x8 af[4], bfr[4];
        #pragma unroll
        for (int i = 0; i < 4; i++)
            af[i] = *(const bf16x8*)&As[b][(wm + i * 16 + m16) * 32 + q * 8];
        #pragma unroll
        for (int j = 0; j < 4; j++)
            bfr[j] = *(const bf16x8*)&Bs[b][(wn + j * 16 + m16) * 32 + q * 8];
        #pragma unroll
        for (int i = 0; i < 4; i++)
            #pragma unroll
            for (int j = 0; j < 4; j++)
                acc[i][j] = __builtin_amdgcn_mfma_f32_16x16x32_bf16(
                    af[i], bfr[j], acc[i][j], 0, 0, 0);
    };

    // prologue: tiles 0,1,2 in flight (12 loads)
    stage(0); stage(1); stage(2);

    // main: 40 K-tiles of 32
    for (int tt = 0; tt < 37; tt++) {
        asm volatile("s_waitcnt vmcnt(8)" ::: "memory");   // tile tt landed
        __builtin_amdgcn_s_barrier();
        stage(tt + 3);                                     // -> buf[(tt-1)&3], safe
        compute(tt);
    }
    asm volatile("s_waitcnt vmcnt(8)" ::: "memory");
    __builtin_amdgcn_s_barrier();
    compute(37);
    asm volatile("s_waitcnt vmcnt(4)" ::: "memory");
    __builtin_amdgcn_s_barrier();
    compute(38);
    asm volatile("s_waitcnt vmcnt(0)" ::: "memory");
    __builtin_amdgcn_s_barrier();
    compute(39);

    // C/D layout: col = lane&15, row = q*4 + reg  [m89-verified]
    #pragma unroll
    for (int i = 0; i < 4; i++)
        #pragma unroll
        for (int j = 0; j < 4; j++)
            #pragma unroll
            for (int r = 0; r < 4; r++) {
                int row = bm + wm + i * 16 + q * 4 + r;
                int col = bn + wn + j * 16 + m16;
                C[(size_t)row * N + col] = acc[i][j][r];
            }
}

// ---------------------------------------------------------------------------
extern "C" void kernel_launch(void* const* d_in, const int* in_sizes, int n_in,
                              void* d_out, int out_size, void* d_ws, size_t ws_size,
                              hipStream_t stream) {
    const float* x    = (const float*)d_in[0];   // [32768][1024]
    const float* pw   = (const float*)d_in[1];   // [64][1024]
    const float* mean = (const float*)d_in[2];   // [64][20]
    const float* emb  = (const float*)d_in[3];   // [1024][1280]
    float* out = (float*)d_out;                  // [32768][1024] fp32

    char* ws = (char*)d_ws;
    u16*   z    = (u16*)(ws);                    // 83,886,080 B
    u16*   wswh = (u16*)(ws + 83886080);         //    131,072 B (16 swizzled 8KB tiles)
    u16*   wswl = (u16*)(ws + 84017152);         //    131,072 B
    u16*   embW = (u16*)(ws + 84148224);         //  2,621,440 B
    // total: 86,769,664 B

    k_norm_w<<<64, 256, 0, stream>>>(pw, wswh, wswl);
    k_cvt<<<(EDIM * FDIM / 4) / 256, 256, 0, stream>>>(emb, embW);
    k_fused<<<M_ROWS / 64, 256, 0, stream>>>(x, wswh, wswl, mean, z);
    k_gemm2<<<dim3(EDIM / 128, M_ROWS / 128), 256, 0, stream>>>(z, embW, out);
}

// Round 4
// 366.016 us; speedup vs baseline: 1.1186x; 1.1186x over previous
//
#include <hip/hip_runtime.h>
#include <hip/hip_bf16.h>
#include <stdint.h>

typedef unsigned short u16;
typedef unsigned int u32;
typedef unsigned long long u64;
typedef __bf16 bf16x8 __attribute__((ext_vector_type(8)));
typedef _Float16 f16x8 __attribute__((ext_vector_type(8)));
typedef float f32x4 __attribute__((ext_vector_type(4)));

#define M_ROWS 32768   // bs*seq
#define DIM    1024    // inp_dim
#define NPROJ  64
#define NBINS  20
#define FDIM   1280    // NPROJ*NBINS
#define EDIM   1024    // emb_dim

// round-to-nearest-even f32 -> bf16 (no NaNs in this problem)
__device__ __forceinline__ u16 f2bf(float f) {
    union { float f; u32 u; } v; v.f = f;
    return (u16)((v.u + 0x7FFFu + ((v.u >> 16) & 1u)) >> 16);
}

__device__ __forceinline__ float wave_sum(float v) {
    #pragma unroll
    for (int o = 32; o > 0; o >>= 1) v += __shfl_down(v, o, 64);
    return v;
}

__device__ __forceinline__ void gl_lds16(const void* g, void* l) {
    __builtin_amdgcn_global_load_lds(
        (const __attribute__((address_space(1))) void*)g,
        (__attribute__((address_space(3))) void*)l, 16, 0, 0);
}

__device__ __forceinline__ f32x4 mfma16(f16x8 a, f16x8 b, f32x4 c) {
    return __builtin_amdgcn_mfma_f32_16x16x32_f16(a, b, c, 0, 0, 0);
}

// scaled f16 split: f = hi + lo*2^-12, lo kept in normal f16 range.
__device__ __forceinline__ void split8(const float* f, f16x8& hi, f16x8& lo) {
    #pragma unroll
    for (int e = 0; e < 8; e++) {
        _Float16 h = (_Float16)f[e];
        hi[e] = h;
        lo[e] = (_Float16)((f[e] - (float)h) * 4096.0f);
    }
}

// ---------------------------------------------------------------------------
// K1: normalize proj_weight rows, split to f16 hi / scaled-lo, and store as
// PRE-SWIZZLED per-K-step tile images so k_fused can global_load_lds them
// linearly and read fragments with the XOR swizzle (G21: both-sides).
// Image: 16 steps x [64 proj][64 k] f16, byte-in-tile = p*128 + (k2 ^ ((p&7)<<4)).
// 64 blocks x 256 threads (one block per proj row, thread t -> k=4t..4t+3).
__global__ void k_norm_w(const float* __restrict__ w, u16* __restrict__ wswh,
                         u16* __restrict__ wswl) {
    int j = blockIdx.x;
    int t = threadIdx.x;
    float4 v = ((const float4*)(w + (size_t)j * DIM))[t];
    float ss = v.x*v.x + v.y*v.y + v.z*v.z + v.w*v.w;
    ss = wave_sum(ss);
    __shared__ float red[4];
    if ((t & 63) == 0) red[t >> 6] = ss;
    __syncthreads();
    float rn = 1.0f / fmaxf(sqrtf(red[0] + red[1] + red[2] + red[3]), 1e-12f);
    float wn[4] = {v.x*rn, v.y*rn, v.z*rn, v.w*rn};
    u64 hp = 0, lp = 0;
    #pragma unroll
    for (int e = 0; e < 4; e++) {
        _Float16 h = (_Float16)wn[e];
        _Float16 l = (_Float16)((wn[e] - (float)h) * 4096.0f);
        union { _Float16 f; u16 u; } ch, cl;
        ch.f = h; cl.f = l;
        hp |= (u64)ch.u << (16 * e);
        lp |= (u64)cl.u << (16 * e);
    }
    int s   = t >> 4;            // K-step (64 fp32 k per step)
    int kk2 = (t & 15) * 8;      // byte col within tile row (k*2)
    int off = s * 8192 + j * 128 + (kk2 ^ ((j & 7) << 4));  // 8B write stays in 16B swz unit
    *(u64*)((char*)wswh + off) = hp;
    *(u64*)((char*)wswl + off) = lp;
}

// ---------------------------------------------------------------------------
// K3: emb_weight fp32 -> bf16, same [EDIM][FDIM] layout. 1280 blocks.
__global__ void k_cvt(const float* __restrict__ s, u16* __restrict__ d) {
    int i = blockIdx.x * 256 + threadIdx.x;
    float4 v = ((const float4*)s)[i];
    ushort4 o; o.x = f2bf(v.x); o.y = f2bf(v.y); o.z = f2bf(v.z); o.w = f2bf(v.w);
    ((ushort4*)d)[i] = o;
}

// ---------------------------------------------------------------------------
// K_FUSED v2 (unchanged this round, for attribution): rnx + GEMM1 + act.
__global__ __launch_bounds__(256) void k_fused(const float* __restrict__ x,
        const u16* __restrict__ wswh, const u16* __restrict__ wswl,
        const float* __restrict__ mean, u16* __restrict__ z) {
    __shared__ u16 Bh[2][4096];      // 8KB/buf: [64 proj][64 k] f16, row-swizzled
    __shared__ u16 Bl[2][4096];
    __shared__ float pl[64 * 68];    // stride 68: 2-way (free) banks both phases
    __shared__ float mlds[64 * 21];  // mean, stride 21 (2-way banks in act)
    __shared__ float rnl[64];

    int t = threadIdx.x;
    int lane = t & 63, wave = t >> 6;
    int m16 = lane & 15, q = lane >> 4;
    int bm = blockIdx.x * 64;
    int wm = wave * 16;
    const float* xr = x + (size_t)(bm + wm + m16) * DIM;   // this lane's A row

    // stage means (read in act phase only; any later barrier covers)
    for (int i = t; i < 64 * 21; i += 256) {
        int j = i / 21, b = i - j * 21;
        if (b < 20) mlds[i] = mean[j * 20 + b];
    }

    f32x4 accA[4], accB[4];
    #pragma unroll
    for (int j = 0; j < 4; j++) { accA[j] = (f32x4){0,0,0,0}; accB[j] = (f32x4){0,0,0,0}; }
    float ssl = 0.f;

    // prologue: stage B(0), load A(0)
    gl_lds16(wswh + (size_t)t * 8,        &Bh[0][t * 8]);
    gl_lds16(wswh + 2048 + (size_t)t * 8, &Bh[0][2048 + t * 8]);
    gl_lds16(wswl + (size_t)t * 8,        &Bl[0][t * 8]);
    gl_lds16(wswl + 2048 + (size_t)t * 8, &Bl[0][2048 + t * 8]);
    float4 c0 = *(const float4*)(xr + q * 8);
    float4 c1 = *(const float4*)(xr + q * 8 + 4);
    float4 c2 = *(const float4*)(xr + q * 8 + 32);
    float4 c3 = *(const float4*)(xr + q * 8 + 36);

    for (int s = 0; s < 16; s++) {
        __syncthreads();   // B(s) staged, A(s) regs arrived (vmcnt drain)

        float4 n0, n1, n2, n3;
        if (s < 15) {
            const u16* sh = wswh + (size_t)(s + 1) * 4096;
            const u16* sl = wswl + (size_t)(s + 1) * 4096;
            u16* dh = &Bh[(s + 1) & 1][0];
            u16* dl = &Bl[(s + 1) & 1][0];
            gl_lds16(sh + t * 8,        dh + t * 8);
            gl_lds16(sh + 2048 + t * 8, dh + 2048 + t * 8);
            gl_lds16(sl + t * 8,        dl + t * 8);
            gl_lds16(sl + 2048 + t * 8, dl + 2048 + t * 8);
            const float* xn = xr + (s + 1) * 64 + q * 8;
            n0 = *(const float4*)(xn);
            n1 = *(const float4*)(xn + 4);
            n2 = *(const float4*)(xn + 32);
            n3 = *(const float4*)(xn + 36);
        }

        ssl += c0.x*c0.x + c0.y*c0.y + c0.z*c0.z + c0.w*c0.w;
        ssl += c1.x*c1.x + c1.y*c1.y + c1.z*c1.z + c1.w*c1.w;
        ssl += c2.x*c2.x + c2.y*c2.y + c2.z*c2.z + c2.w*c2.w;
        ssl += c3.x*c3.x + c3.y*c3.y + c3.z*c3.z + c3.w*c3.w;

        float av0[8] = {c0.x, c0.y, c0.z, c0.w, c1.x, c1.y, c1.z, c1.w};
        float av1[8] = {c2.x, c2.y, c2.z, c2.w, c3.x, c3.y, c3.z, c3.w};
        f16x8 ah[2], al[2];
        split8(av0, ah[0], al[0]);
        split8(av1, ah[1], al[1]);

        const char* bhp = (const char*)&Bh[s & 1][0];
        const char* blp = (const char*)&Bl[s & 1][0];
        #pragma unroll
        for (int ks = 0; ks < 2; ks++) {
            #pragma unroll
            for (int j = 0; j < 4; j++) {
                int P = j * 16 + m16;
                int off = P * 128 + ((q * 16 + ks * 64) ^ ((m16 & 7) << 4));
                f16x8 bh = *(const f16x8*)(bhp + off);
                f16x8 bl = *(const f16x8*)(blp + off);
                accA[j] = mfma16(ah[ks], bh, accA[j]);
                accB[j] = mfma16(ah[ks], bl, accB[j]);
                accB[j] = mfma16(al[ks], bh, accB[j]);
            }
        }
        c0 = n0; c1 = n1; c2 = n2; c3 = n3;
    }

    // --- rnx: 4 q-lanes of a row hold disjoint partials
    ssl += __shfl_xor(ssl, 16, 64);
    ssl += __shfl_xor(ssl, 32, 64);
    if (q == 0) rnl[wm + m16] = 1.0f / fmaxf(sqrtf(ssl), 1e-12f);
    __syncthreads();

    // --- p = (accA + accB*2^-12) * rnx -> pl   (C layout: row q*4+r, col m16)
    #pragma unroll
    for (int r = 0; r < 4; r++) {
        int row = wm + q * 4 + r;
        float rr = rnl[row];
        #pragma unroll
        for (int j = 0; j < 4; j++)
            pl[row * 68 + j * 16 + m16] =
                (accA[j][r] + accB[j][r] * 2.44140625e-4f) * rr;
    }
    __syncthreads();

    // --- act: thread owns projs 4c..4c+3 of rows rt+16*it -> 160B z chunks
    int c = t & 15;
    int rt = t >> 4;
    #pragma unroll 1
    for (int it = 0; it < 4; it++) {
        int row = rt + 16 * it;
        const float* prow = &pl[row * 68 + c * 4];
        float pp[4] = {prow[0], prow[1], prow[2], prow[3]};
        u32 packed[40];
        #pragma unroll
        for (int jj = 0; jj < 4; jj++) {
            float pv = pp[jj];
            const float* mj = &mlds[(c * 4 + jj) * 21];
            float act[NBINS];
            float top0 = -1e30f, top1 = -1e30f, top2 = -1e30f, top3 = -1e30f;
            #pragma unroll
            for (int b = 0; b < NBINS; b++) {
                float d = pv - mj[b];
                float a = __expf(-50.0f * d * d);   // 0.5/sigma2 = 50
                act[b] = a;
                if (a > top3) {
                    if (a > top0)      { top3 = top2; top2 = top1; top1 = top0; top0 = a; }
                    else if (a > top1) { top3 = top2; top2 = top1; top1 = a; }
                    else if (a > top2) { top3 = top2; top2 = a; }
                    else               { top3 = a; }
                }
            }
            float ss = 0.f;
            #pragma unroll
            for (int b = 0; b < NBINS; b++) {
                float a = (act[b] >= top3) ? act[b] : 0.0f;   // keep ties
                act[b] = a;
                ss += a * a;
            }
            float rr = 1.0f / fmaxf(sqrtf(ss), 1e-12f);
            #pragma unroll
            for (int i2 = 0; i2 < 10; i2++) {
                u32 lo = f2bf(act[2 * i2] * rr);
                u32 hi = f2bf(act[2 * i2 + 1] * rr);
                packed[jj * 10 + i2] = lo | (hi << 16);
            }
        }
        uint4* zp = (uint4*)(z + ((size_t)(bm + row) * FDIM + c * 80));
        #pragma unroll
        for (int u2 = 0; u2 < 10; u2++)
            zp[u2] = make_uint4(packed[4*u2], packed[4*u2+1], packed[4*u2+2], packed[4*u2+3]);
    }
}

// ---------------------------------------------------------------------------
// K6 v3: GEMM2 bf16 MFMA, BK=64 single-buffer 2-barrier (m97 sync pattern),
// T2 swizzle via G21 both-sides: LDS tile [128 rows][64 k] (128B rows) would
// be a 16-way conflict linear (every row starts at bank 0). Fix: stage with
// SOURCE k-granule g^=(row&7) (permutes 16B granules within the same 128B
// row chunk -> still coalesced, producers unchanged), read frags with the
// same XOR -> 8 distinct bank groups per 16-lane group = conflict-free.
// Depth-3 dynamic-buffer pipeline REVERTED (R3: VALU addr-calc flood,
// 141->151us). Static addressing, full unroll, 20 K-tiles.
__global__ __launch_bounds__(256) void k_gemm2(const u16* __restrict__ A,
                                               const u16* __restrict__ B,
                                               float* __restrict__ C) {
    const int K = FDIM, N = EDIM;
    __shared__ u16 As[128 * 64];   // 16KB, [row][64k] granule-swizzled
    __shared__ u16 Bs[128 * 64];   // 16KB
    int t = threadIdx.x;
    int lane = t & 63, wave = t >> 6;
    int sfl  = (blockIdx.y << 3) | blockIdx.x;        // hw dispatch order (x fastest)
    int tile = ((sfl & 7) << 8) | (sfl >> 3);         // xcd*256 + idx-in-xcd
    int bm = (tile >> 3) * 128;                       // 0..255 M-tiles
    int bn = (tile & 7) * 128;                        // 0..7   N-tiles
    int wm = (wave >> 1) * 64, wn = (wave & 1) * 64;
    int m16 = lane & 15, q = lane >> 4;

    f32x4 zero = {0.f, 0.f, 0.f, 0.f};
    f32x4 acc[4][4];
    #pragma unroll
    for (int i = 0; i < 4; i++)
        #pragma unroll
        for (int j = 0; j < 4; j++) acc[i][j] = zero;

    // staging: round r covers rows r*32..r*32+31; thread t -> row r*32+(t>>3),
    // granule g = t&7. LDS slot = linear t*16 + r*4096 bytes (wave-uniform
    // base + lane*16 ✓). Source granule = g ^ (row&7); row&7 == (t>>3)&7
    // invariant across rounds (32 ≡ 0 mod 8).
    int srow = t >> 3;                  // 0..31
    int gsw  = (t & 7) ^ (srow & 7);    // swizzled source granule
    const u16* gA = A + (size_t)(bm + srow) * K + gsw * 8;
    const u16* gB = B + (size_t)(bn + srow) * K + gsw * 8;
    u16* la = &As[t * 8];
    u16* lb = &Bs[t * 8];

    // frag read offsets (u16 idx): row*64 + ((ks*32 + q*8) ^ ((m16&7)<<3))
    int swz = (m16 & 7) << 3;

    for (int tt = 0; tt < 20; tt++) {
        int k0 = tt * 64;
        #pragma unroll
        for (int r = 0; r < 4; r++) {
            gl_lds16(gA + (size_t)(32 * r) * K + k0, la + r * 2048);
            gl_lds16(gB + (size_t)(32 * r) * K + k0, lb + r * 2048);
        }
        __syncthreads();   // compiler drains vmcnt before s_barrier
        #pragma unroll
        for (int ks = 0; ks < 2; ks++) {
            bf16x8 af[4], bfr[4];
            #pragma unroll
            for (int i = 0; i < 4; i++)
                af[i] = *(const bf16x8*)&As[(wm + i * 16 + m16) * 64 + ((ks * 32 + q * 8) ^ swz)];
            #pragma unroll
            for (int j = 0; j < 4; j++)
                bfr[j] = *(const bf16x8*)&Bs[(wn + j * 16 + m16) * 64 + ((ks * 32 + q * 8) ^ swz)];
            #pragma unroll
            for (int i = 0; i < 4; i++)
                #pragma unroll
                for (int j = 0; j < 4; j++)
                    acc[i][j] = __builtin_amdgcn_mfma_f32_16x16x32_bf16(
                        af[i], bfr[j], acc[i][j], 0, 0, 0);
        }
        __syncthreads();
    }

    // C/D layout: col = lane&15, row = q*4 + reg  [m89-verified]
    #pragma unroll
    for (int i = 0; i < 4; i++)
        #pragma unroll
        for (int j = 0; j < 4; j++)
            #pragma unroll
            for (int r = 0; r < 4; r++) {
                int row = bm + wm + i * 16 + q * 4 + r;
                int col = bn + wn + j * 16 + m16;
                C[(size_t)row * N + col] = acc[i][j][r];
            }
}

// ---------------------------------------------------------------------------
extern "C" void kernel_launch(void* const* d_in, const int* in_sizes, int n_in,
                              void* d_out, int out_size, void* d_ws, size_t ws_size,
                              hipStream_t stream) {
    const float* x    = (const float*)d_in[0];   // [32768][1024]
    const float* pw   = (const float*)d_in[1];   // [64][1024]
    const float* mean = (const float*)d_in[2];   // [64][20]
    const float* emb  = (const float*)d_in[3];   // [1024][1280]
    float* out = (float*)d_out;                  // [32768][1024] fp32

    char* ws = (char*)d_ws;
    u16*   z    = (u16*)(ws);                    // 83,886,080 B
    u16*   wswh = (u16*)(ws + 83886080);         //    131,072 B (16 swizzled 8KB tiles)
    u16*   wswl = (u16*)(ws + 84017152);         //    131,072 B
    u16*   embW = (u16*)(ws + 84148224);         //  2,621,440 B
    // total: 86,769,664 B

    k_norm_w<<<64, 256, 0, stream>>>(pw, wswh, wswl);
    k_cvt<<<(EDIM * FDIM / 4) / 256, 256, 0, stream>>>(emb, embW);
    k_fused<<<M_ROWS / 64, 256, 0, stream>>>(x, wswh, wswl, mean, z);
    k_gemm2<<<dim3(EDIM / 128, M_ROWS / 128), 256, 0, stream>>>(z, embW, out);
}